// Round 8
// baseline (264.939 us; speedup 1.0000x reference)
//
#include <hip/hip_runtime.h>
#include <hip/hip_fp16.h>

// Problem constants
#define IMGS 2
#define OW 90
#define NP 8100                // 90*90 valid patches
#define HW 96
#define CH_STRIDE 9216
#define IMG_STRIDE 27648
#define KP 192                 // padded row stride in halfs (data to 159; rest zero)
#define MP 8192                // padded patch count
#define ALPHA 0.05f
#define INV_D (1.0f/147.0f)
#define PAD_SENTINEL 60000.0f  // finite fp16 value >> any real (x2-2c) magnitude

typedef _Float16 half8 __attribute__((ext_vector_type(8)));
typedef float floatx4 __attribute__((ext_vector_type(4)));

// async global->LDS, 16B per lane; LDS dest = uniform base + lane*16
#define GLD_LDS16(gp, lp)                                                     \
    __builtin_amdgcn_global_load_lds(                                         \
        (const __attribute__((address_space(1))) void*)(gp),                  \
        (__attribute__((address_space(3))) void*)(lp), 16, 0, 0)

// ws byte offsets
// A matrix = -2*Y with slot147 = 1.0      (fp16 [2][8192][192])
// B matrix =    X with slot147 = x2_i (valid) / 60000 (pad row)
#define XP_OFF   0
#define YP_OFF   (XP_OFF + IMGS*MP*KP*2)
#define N2Y_OFF  (YP_OFF + IMGS*MP*KP*2)        // float [2][8192] (y norms)
#define RMIN_OFF (N2Y_OFF + IMGS*MP*4)          // int-bits float [2][8192]
#define RINV_OFF (RMIN_OFF + IMGS*MP*4)         // r' = INV_D*rinv (0 for pad rows)
#define AY_OFF   (RINV_OFF + IMGS*MP*4)         // ay = r'*y2 (+inf for pad rows)
#define CMIN_OFF (AY_OFF + IMGS*MP*4)

// -------- fused build + norms + min-init ----------------------------------
__global__ __launch_bounds__(256) void k_build(const float* __restrict__ x,
                                               const float* __restrict__ y,
                                               char* __restrict__ wsb) {
    int tid = threadIdx.x;
    int hwv = tid >> 5;                      // half-wave 0..7
    int l = tid & 31;
    int grow = blockIdx.x * 8 + hwv;         // 0..32767
    int tensor = grow >> 14;                 // 0 = x(B), 1 = y(A)
    int img = (grow >> 13) & 1;
    int row = grow & (MP - 1);
    const float* src = (tensor ? y : x) + img * IMG_STRIDE;
    int py = row / OW, px = row - py * OW;
    bool rvalid = row < NP;

    float vals[8];
#pragma unroll
    for (int j = 0; j < 8; j++) {
        int k = l * 8 + j;
        float v = 0.0f;
        if (rvalid && k < 147) {
            int c = k / 49;
            int rm = k - c * 49;
            int dy = rm / 7, dx = rm - dy * 7;
            v = src[c * CH_STRIDE + (py + dy) * HW + px + dx];
        }
        vals[j] = (float)(_Float16)v;        // round through fp16 (ref casts first)
    }
    float ss16 = 0.0f;
#pragma unroll
    for (int j = 0; j < 8; j++) ss16 = fmaf(vals[j], vals[j], ss16);
#pragma unroll
    for (int m = 1; m < 32; m <<= 1) ss16 += __shfl_xor(ss16, m, 32);

    if (tensor && l == 0)
        ((float*)(wsb + N2Y_OFF))[img * MP + row] = rvalid ? ss16 : 0.0f;

    half8 h;
#pragma unroll
    for (int j = 0; j < 8; j++) {
        float f = vals[j];
        if (tensor) f *= -2.0f;              // A = -2*Y (exact in fp16)
        h[j] = (_Float16)f;
    }
    if (l == 18) {                           // k = 147 is j=3 of chunk 18
        h[3] = tensor ? (_Float16)1.0f
                      : (rvalid ? (_Float16)ss16 : (_Float16)PAD_SENTINEL);
    }
    if (l < 24) {
        _Float16* dst = (_Float16*)(wsb + (tensor ? YP_OFF : XP_OFF)) +
                        ((size_t)img * MP + row) * KP + l * 8;
        *(half8*)dst = h;
    }
    if (tid < 8) {                           // min-array init (ws is re-poisoned)
        int gi = blockIdx.x * 8 + tid;
        if (gi < IMGS * MP)
            ((int*)(wsb + RMIN_OFF))[gi] = 0x7f800000;
        else
            ((int*)(wsb + CMIN_OFF))[gi - IMGS * MP] = 0x7f800000;
    }
}

// -------- resident-operand streaming GEMM + register min reduction --------
// SINGLE 40KB LDS tile buffer (no double-buffer) + 1KB consts -> 3 blocks/CU;
// grid 8x64x2 = 1024 blocks so ~3 de-phased blocks/CU hide each other's
// fill-drain (fill ~40KB, ~1/4 of a compute phase at L2 BW). Resident tile's
// 20 fragments live in VGPRs; launch_bounds(256,3) caps regs at ~170
// (rf 80 + acc 64 + addressing). PASS2 row-consts go through LDS, not regs.
// PASS 1: resident = A (-2Y, rtile), stream B (X). rowmin in regs.
// PASS 2: resident = B (X, rtile), stream A. colmin in regs (r'*acc+ay).
template <int PASS>
__global__ __launch_bounds__(256, 3) void k_gemm(char* __restrict__ wsb) {
    __shared__ __align__(16) _Float16 R1[128 * 128];   // 32 KB, K-chunks 0..15
    __shared__ __align__(16) _Float16 R2[128 * 32];    //  8 KB, K-chunks 16..19
    __shared__ float rsld[128];                        // PASS2: r' per streamed row
    __shared__ float ayld[128];                        // PASS2: ay per streamed row
    int tid = threadIdx.x;
    int lane = tid & 63, w = tid >> 6;
    int wm = (w >> 1) * 64, wn = (w & 1) * 64;
    int quad = lane >> 4, col16 = lane & 15;
    int q = blockIdx.x;                      // eighth: 8 streamed tiles
    int rtile = blockIdx.y;                  // resident tile index
    int img = blockIdx.z;

    const _Float16* Res = (const _Float16*)(wsb + (PASS == 1 ? YP_OFF : XP_OFF)) +
                          ((size_t)img * MP + rtile * 128) * KP;
    const _Float16* Str = (const _Float16*)(wsb + (PASS == 1 ? XP_OFF : YP_OFF)) +
                          (size_t)img * MP * KP;

    // staging lane roles (constant)
    int roff1 = lane >> 4, cc1 = lane & 15;  // region1: 4 rows/GLD
    int roff2 = lane >> 2, cc2 = lane & 3;   // region2: 16 rows/GLD
#define STAGE(Mat)                                                             \
    {                                                                          \
        int rbase = w * 32;                                                    \
        _Pragma("unroll") for (int g = 0; g < 8; g++) {                        \
            int r = rbase + g * 4 + roff1;                                     \
            int gc = cc1 ^ (r & 7);                                            \
            GLD_LDS16((Mat) + (size_t)r * KP + gc * 8, &R1[(rbase + g * 4) * 128]); \
        }                                                                      \
        _Pragma("unroll") for (int g = 0; g < 2; g++) {                        \
            int r = rbase + g * 16 + roff2;                                    \
            int gc = cc2 ^ ((r >> 1) & 3);                                     \
            GLD_LDS16((Mat) + (size_t)r * KP + 128 + gc * 8, &R2[(rbase + g * 16) * 32]); \
        }                                                                      \
    }

#define READFRAG(row, ks)                                                      \
    ((ks) < 4 ? *(const half8*)(&R1[(row) * 128 + ((((ks) * 4 + quad) ^ ((row) & 7)) * 8)]) \
              : *(const half8*)(&R2[(row) * 32 + ((quad ^ (((row) >> 1) & 3)) * 8)]))

    // ---- prologue: resident tile -> LDS -> registers ----
    STAGE(Res);
    __syncthreads();
    half8 rf[4][5];
    int rrow0 = (PASS == 1) ? wm : wn;
#pragma unroll
    for (int i = 0; i < 4; i++)
#pragma unroll
        for (int c = 0; c < 5; c++)
            rf[i][c] = READFRAG(rrow0 + i * 16 + col16, c);

    float rmin[4][4];                        // PASS1: per-(mi,r) row mins
    float cmin[4];                           // PASS2: per-ni col mins
#pragma unroll
    for (int i = 0; i < 4; i++) {
        cmin[i] = 1e30f;
#pragma unroll
        for (int j = 0; j < 4; j++) rmin[i][j] = 1e30f;
    }
    int srow0 = (PASS == 1) ? wn : wm;
    const float* RIp = (const float*)(wsb + RINV_OFF) + img * MP;
    const float* AYp = (const float*)(wsb + AY_OFF) + img * MP;

    for (int s = 0; s < 8; s++) {
        __syncthreads();                     // all reads of buffer done
        STAGE(Str + (size_t)(q * 8 + s) * 128 * KP);
        if (PASS == 2 && tid < 128) {
            int gr = (q * 8 + s) * 128 + tid;
            rsld[tid] = RIp[gr];
            ayld[tid] = AYp[gr];
        }
        __syncthreads();                     // fill + consts visible (drains vmcnt)
        floatx4 acc[4][4];
#pragma unroll
        for (int i = 0; i < 4; i++)
#pragma unroll
            for (int j = 0; j < 4; j++) acc[i][j] = (floatx4){0.f, 0.f, 0.f, 0.f};
#pragma unroll
        for (int ks = 0; ks < 5; ks++) {
            half8 sf[4];
#pragma unroll
            for (int i = 0; i < 4; i++)
                sf[i] = READFRAG(srow0 + i * 16 + col16, ks);
#pragma unroll
            for (int mi = 0; mi < 4; mi++)
#pragma unroll
                for (int ni = 0; ni < 4; ni++)
                    acc[mi][ni] = __builtin_amdgcn_mfma_f32_16x16x32_f16(
                        (PASS == 1) ? rf[mi][ks] : sf[mi],
                        (PASS == 1) ? sf[ni] : rf[ni][ks],
                        acc[mi][ni], 0, 0, 0);
        }
        // fold into register mins (pad cols/rows auto-masked: sentinel / ay=inf)
        if (PASS == 1) {
#pragma unroll
            for (int mi = 0; mi < 4; mi++)
#pragma unroll
                for (int r = 0; r < 4; r++) {
                    float m4 = fminf(fminf(acc[mi][0][r], acc[mi][1][r]),
                                     fminf(acc[mi][2][r], acc[mi][3][r]));
                    rmin[mi][r] = fminf(rmin[mi][r], m4);
                }
        } else {
#pragma unroll
            for (int mi = 0; mi < 4; mi++)
#pragma unroll
                for (int r = 0; r < 4; r++) {
                    int row_l = wm + mi * 16 + quad * 4 + r;
                    float rr = rsld[row_l];  // broadcast within quad-group
                    float aa = ayld[row_l];
#pragma unroll
                    for (int ni = 0; ni < 4; ni++)
                        cmin[ni] = fminf(cmin[ni],
                                         fmaf(rr, acc[mi][ni][r], aa));
                }
        }
    }

    // ---- final reduction: shuffle + one global atomicMin per row/col -----
    if (PASS == 1) {
#pragma unroll
        for (int mi = 0; mi < 4; mi++)
#pragma unroll
            for (int r = 0; r < 4; r++) {
                float best = rmin[mi][r];
                best = fminf(best, __shfl_xor(best, 1, 16));
                best = fminf(best, __shfl_xor(best, 2, 16));
                best = fminf(best, __shfl_xor(best, 4, 16));
                best = fminf(best, __shfl_xor(best, 8, 16));
                int rg = rtile * 128 + wm + mi * 16 + quad * 4 + r;
                if (col16 == 0 && rg < NP)
                    atomicMin((int*)(wsb + RMIN_OFF) + img * MP + rg,
                              __float_as_int(best));
            }
    } else {
#pragma unroll
        for (int ni = 0; ni < 4; ni++) {
            float best = cmin[ni];
            best = fminf(best, __shfl_xor(best, 16, 64));
            best = fminf(best, __shfl_xor(best, 32, 64));
            if (quad == 0)
                atomicMin((int*)(wsb + CMIN_OFF) + img * MP +
                              rtile * 128 + wn + ni * 16 + col16,
                          __float_as_int(best));
        }
    }
}

// -------- rinv: finish rowmin, bake constants for pass 2 ------------------
__global__ __launch_bounds__(256) void k_rinv(char* __restrict__ wsb) {
    int gid = blockIdx.x * 256 + threadIdx.x;      // 2*8192
    float rm = __int_as_float(((const int*)(wsb + RMIN_OFF))[gid]);
    float y2 = ((const float*)(wsb + N2Y_OFF))[gid];
    float d = (y2 + rm) * INV_D;                   // rowmin distance
    float rp = INV_D / (d + ALPHA);                // r' = INV_D * rinv
    bool valid = (gid & (MP - 1)) < NP;
    ((float*)(wsb + RINV_OFF))[gid] = valid ? rp : 0.0f;
    ((float*)(wsb + AY_OFF))[gid] = valid ? rp * y2 : __builtin_huge_valf();
}

// -------- finalize: mean over inputs, mean over images --------------------
__global__ __launch_bounds__(256) void k_final(const char* __restrict__ wsb,
                                               float* __restrict__ out) {
    __shared__ float red[256];
    int tid = threadIdx.x;
    const int* cm = (const int*)(wsb + CMIN_OFF);
    float s = 0.0f;
    for (int i = tid; i < NP; i += 256) {
        s += __int_as_float(cm[i]);
        s += __int_as_float(cm[MP + i]);
    }
    red[tid] = s;
    __syncthreads();
    for (int st = 128; st > 0; st >>= 1) {
        if (tid < st) red[tid] += red[tid + st];
        __syncthreads();
    }
    if (tid == 0) out[0] = red[0] * (0.5f / NP);
}

extern "C" void kernel_launch(void* const* d_in, const int* in_sizes, int n_in,
                              void* d_out, int out_size, void* d_ws, size_t ws_size,
                              hipStream_t stream) {
    const float* x = (const float*)d_in[0];
    const float* y = (const float*)d_in[1];
    char* wsb = (char*)d_ws;
    float* out = (float*)d_out;

    k_build<<<4096, 256, 0, stream>>>(x, y, wsb);
    k_gemm<1><<<dim3(8, 64, IMGS), 256, 0, stream>>>(wsb);
    k_rinv<<<(IMGS * MP) / 256, 256, 0, stream>>>(wsb);
    k_gemm<2><<<dim3(8, 64, IMGS), 256, 0, stream>>>(wsb);
    k_final<<<1, 256, 0, stream>>>(wsb, out);
}

// Round 9
// 167.244 us; speedup vs baseline: 1.5841x; 1.5841x over previous
//
#include <hip/hip_runtime.h>
#include <hip/hip_fp16.h>

// Problem constants
#define IMGS 2
#define OW 90
#define NP 8100                // 90*90 valid patches
#define HW 96
#define CH_STRIDE 9216
#define IMG_STRIDE 27648
#define KP 192                 // padded row stride in halfs (data to 159; rest zero)
#define MP 8192                // padded patch count
#define ALPHA 0.05f
#define INV_D (1.0f/147.0f)
#define PAD_SENTINEL 60000.0f  // finite fp16 value >> any real distance magnitude

typedef _Float16 half8 __attribute__((ext_vector_type(8)));
typedef float floatx4 __attribute__((ext_vector_type(4)));

// async global->LDS, 16B per lane; LDS dest = uniform base + lane*16
#define GLD_LDS16(gp, lp)                                                     \
    __builtin_amdgcn_global_load_lds(                                         \
        (const __attribute__((address_space(1))) void*)(gp),                  \
        (__attribute__((address_space(3))) void*)(lp), 16, 0, 0)

// ws byte offsets
// A matrix = -2*Y, slot147 = 1.0, slot148 = 0   (fp16 [2][8192][192])
//   (after k_rescale: row scaled by r', slot147 = r', slot148 = r'*y2 / 60000)
// B matrix =    X, slot147 = x2 (valid) / 60000 (pad), slot148 = 1 (valid) / 0
#define XP_OFF   0
#define YP_OFF   (XP_OFF + IMGS*MP*KP*2)
#define N2Y_OFF  (YP_OFF + IMGS*MP*KP*2)        // float [2][8192] (y norms)
#define RMIN_OFF (N2Y_OFF + IMGS*MP*4)          // int-bits float [2][8192]
#define CMIN_OFF (RMIN_OFF + IMGS*MP*4)

// -------- fused build + norms + min-init ----------------------------------
__global__ __launch_bounds__(256) void k_build(const float* __restrict__ x,
                                               const float* __restrict__ y,
                                               char* __restrict__ wsb) {
    int tid = threadIdx.x;
    int hwv = tid >> 5;                      // half-wave 0..7
    int l = tid & 31;
    int grow = blockIdx.x * 8 + hwv;         // 0..32767
    int tensor = grow >> 14;                 // 0 = x(B), 1 = y(A)
    int img = (grow >> 13) & 1;
    int row = grow & (MP - 1);
    const float* src = (tensor ? y : x) + img * IMG_STRIDE;
    int py = row / OW, px = row - py * OW;
    bool rvalid = row < NP;

    float vals[8];
#pragma unroll
    for (int j = 0; j < 8; j++) {
        int k = l * 8 + j;
        float v = 0.0f;
        if (rvalid && k < 147) {
            int c = k / 49;
            int rm = k - c * 49;
            int dy = rm / 7, dx = rm - dy * 7;
            v = src[c * CH_STRIDE + (py + dy) * HW + px + dx];
        }
        vals[j] = (float)(_Float16)v;        // round through fp16 (ref casts first)
    }
    float ss16 = 0.0f;
#pragma unroll
    for (int j = 0; j < 8; j++) ss16 = fmaf(vals[j], vals[j], ss16);
#pragma unroll
    for (int m = 1; m < 32; m <<= 1) ss16 += __shfl_xor(ss16, m, 32);

    if (tensor && l == 0)
        ((float*)(wsb + N2Y_OFF))[img * MP + row] = rvalid ? ss16 : 0.0f;

    half8 h;
#pragma unroll
    for (int j = 0; j < 8; j++) {
        float f = vals[j];
        if (tensor) f *= -2.0f;              // A = -2*Y (exact in fp16)
        h[j] = (_Float16)f;
    }
    if (l == 18) {                           // k=147 is j=3, k=148 is j=4
        h[3] = tensor ? (_Float16)1.0f
                      : (rvalid ? (_Float16)ss16 : (_Float16)PAD_SENTINEL);
        if (!tensor) h[4] = rvalid ? (_Float16)1.0f : (_Float16)0.0f;
    }
    if (l < 24) {
        _Float16* dst = (_Float16*)(wsb + (tensor ? YP_OFF : XP_OFF)) +
                        ((size_t)img * MP + row) * KP + l * 8;
        *(half8*)dst = h;
    }
    if (tid < 8) {                           // min-array init (ws is re-poisoned)
        int gi = blockIdx.x * 8 + tid;
        if (gi < IMGS * MP)
            ((int*)(wsb + RMIN_OFF))[gi] = 0x7f800000;
        else
            ((int*)(wsb + CMIN_OFF))[gi - IMGS * MP] = 0x7f800000;
    }
}

// -------- resident-operand streaming GEMM, 64-row streamed tiles ----------
// r7's proven prefetch-after-barrier double buffer, shrunk to 2x20KB so LDS
// = 40KB -> 3 blocks/CU; launch_bounds(256,3) caps VGPR ~170 -> 12 waves/CU.
// Resident 128 rows live in VGPRs (rf[4][5]); streamed 64-row tiles: region1
// rows 128 halfs (16 chunks, swizzle c^(r&7)), region2 rows 32 halfs
// (4 chunks, swizzle c^((r>>1)&3)); both 2-way on b128 reads -> free.
// PASS 1: resident = A (-2Y, rtile), stream B (X): acc = x2-2c; rowmin.
// PASS 2: resident = B (X, rtile), stream rescaled A: acc = r'(x2+y2-2c);
//         colmin. Both folds are pure fmin (no consts in the loop).
#define R2OFF 8192   // halfs: region2 base within a 10240-half buffer

#define STAGE64(mat, buf)                                                      \
    {                                                                          \
        int rb_ = w * 16;                                                      \
        _Pragma("unroll") for (int g_ = 0; g_ < 4; g_++) {                     \
            int r_ = rb_ + g_ * 4 + (lane >> 4);                               \
            int gc_ = (lane & 15) ^ (r_ & 7);                                  \
            GLD_LDS16((mat) + (size_t)r_ * KP + gc_ * 8,                       \
                      (buf) + (rb_ + g_ * 4) * 128);                           \
        }                                                                      \
        int r2_ = rb_ + (lane >> 2);                                           \
        int gc2_ = (lane & 3) ^ ((r2_ >> 1) & 3);                              \
        GLD_LDS16((mat) + (size_t)r2_ * KP + 128 + gc2_ * 8,                   \
                  (buf) + R2OFF + rb_ * 32);                                   \
    }

#define READFRAG(buf, row, ks)                                                 \
    ((ks) < 4 ? *(const half8*)(&(buf)[(row) * 128 +                           \
                                       ((((ks) * 4 + quad) ^ ((row) & 7)) * 8)]) \
              : *(const half8*)(&(buf)[R2OFF + (row) * 32 +                    \
                                       ((quad ^ (((row) >> 1) & 3)) * 8)]))

template <int PASS>
__global__ __launch_bounds__(256, 3) void k_gemm(char* __restrict__ wsb) {
    __shared__ __align__(16) _Float16 Buf[2][10240];   // 2 x 20 KB
    int tid = threadIdx.x;
    int lane = tid & 63, w = tid >> 6;
    int quad = lane >> 4, col16 = lane & 15;
    int q = blockIdx.x;                      // octant: 16 streamed 64-row tiles
    int rtile = blockIdx.y;                  // resident 128-row tile
    int img = blockIdx.z;

    const _Float16* Res = (const _Float16*)(wsb + (PASS == 1 ? YP_OFF : XP_OFF)) +
                          ((size_t)img * MP + rtile * 128) * KP;
    const _Float16* Str = (const _Float16*)(wsb + (PASS == 1 ? XP_OFF : YP_OFF)) +
                          (size_t)img * MP * KP;

    // ---- prologue: resident 128 rows -> both buffers -> registers ----
    STAGE64(Res, Buf[0]);
    STAGE64(Res + (size_t)64 * KP, Buf[1]);
    __syncthreads();
    half8 rf[4][5];                          // waves 0,1: rows 0..63 (Buf0);
    const _Float16* rb = Buf[w >> 1];        // waves 2,3: rows 64..127 (Buf1)
#pragma unroll
    for (int i = 0; i < 4; i++)
#pragma unroll
        for (int c = 0; c < 5; c++)
            rf[i][c] = READFRAG(rb, i * 16 + col16, c);
    __syncthreads();                         // rf reads drained before overwrite
    STAGE64(Str + (size_t)(q * 16) * 64 * KP, Buf[0]);   // tile 0 -> buf0

    float rmin[4][4];                        // PASS1 accumulators
    float cmin[4];                           // PASS2 accumulators
#pragma unroll
    for (int i = 0; i < 4; i++) {
        cmin[i] = 1e30f;
#pragma unroll
        for (int j = 0; j < 4; j++) rmin[i][j] = 1e30f;
    }
    int s0 = (w & 1) * 32;                   // wave's streamed half

    for (int s = 0; s < 16; s++) {
        __syncthreads();                     // drains prefetch of s; reads of s-1 done
        if (s < 15)
            STAGE64(Str + (size_t)(q * 16 + s + 1) * 64 * KP, Buf[(s + 1) & 1]);
        const _Float16* sb = Buf[s & 1];
        floatx4 acc[8];
#pragma unroll
        for (int i = 0; i < 8; i++) acc[i] = (floatx4){0.f, 0.f, 0.f, 0.f};
#pragma unroll
        for (int ks = 0; ks < 5; ks++) {
            half8 sf0 = READFRAG(sb, s0 + col16, ks);
            half8 sf1 = READFRAG(sb, s0 + 16 + col16, ks);
            if (PASS == 1) {
#pragma unroll
                for (int i = 0; i < 4; i++) {
                    acc[i * 2] = __builtin_amdgcn_mfma_f32_16x16x32_f16(
                        rf[i][ks], sf0, acc[i * 2], 0, 0, 0);
                    acc[i * 2 + 1] = __builtin_amdgcn_mfma_f32_16x16x32_f16(
                        rf[i][ks], sf1, acc[i * 2 + 1], 0, 0, 0);
                }
            } else {
#pragma unroll
                for (int i = 0; i < 4; i++) {
                    acc[i] = __builtin_amdgcn_mfma_f32_16x16x32_f16(
                        sf0, rf[i][ks], acc[i], 0, 0, 0);
                    acc[4 + i] = __builtin_amdgcn_mfma_f32_16x16x32_f16(
                        sf1, rf[i][ks], acc[4 + i], 0, 0, 0);
                }
            }
        }
        // pure fmin fold (pad rows/cols auto-masked by baked sentinels)
        if (PASS == 1) {
#pragma unroll
            for (int i = 0; i < 4; i++)
#pragma unroll
                for (int r = 0; r < 4; r++)
                    rmin[i][r] = fminf(rmin[i][r],
                                       fminf(acc[i * 2][r], acc[i * 2 + 1][r]));
        } else {
#pragma unroll
            for (int i = 0; i < 4; i++)
#pragma unroll
                for (int r = 0; r < 4; r++)
                    cmin[i] = fminf(cmin[i], fminf(acc[i][r], acc[4 + i][r]));
        }
    }

    // ---- final: shuffle reduce + one atomicMin per row/col ----
    if (PASS == 1) {
#pragma unroll
        for (int i = 0; i < 4; i++)
#pragma unroll
            for (int r = 0; r < 4; r++) {
                float best = rmin[i][r];
                best = fminf(best, __shfl_xor(best, 1, 16));
                best = fminf(best, __shfl_xor(best, 2, 16));
                best = fminf(best, __shfl_xor(best, 4, 16));
                best = fminf(best, __shfl_xor(best, 8, 16));
                int rg = rtile * 128 + (w >> 1) * 64 + i * 16 + quad * 4 + r;
                if (col16 == 0 && rg < NP)
                    atomicMin((int*)(wsb + RMIN_OFF) + img * MP + rg,
                              __float_as_int(best));
            }
    } else {
#pragma unroll
        for (int i = 0; i < 4; i++) {
            float best = cmin[i];
            best = fminf(best, __shfl_xor(best, 16, 64));
            best = fminf(best, __shfl_xor(best, 32, 64));
            int cg = rtile * 128 + (w >> 1) * 64 + i * 16 + col16;
            if (quad == 0)
                atomicMin((int*)(wsb + CMIN_OFF) + img * MP + cg,
                          __float_as_int(best));
        }
    }
}

// -------- rescale A in place: A2 = r' * A, slot148 = r'*y2 ---------------
// r' = INV_D / ((y2+rmin)*INV_D + alpha). Pad rows: RMIN=+inf -> r'=0 ->
// row zeroed; slot148 = 60000 keeps them out of every col-min.
__global__ __launch_bounds__(256) void k_rescale(char* __restrict__ wsb) {
    int gid = blockIdx.x * 256 + threadIdx.x;      // 2*8192*24
    int chunk = gid % 24;
    int row = gid / 24;                            // [img*8192 + r]
    int r = row & (MP - 1);
    float rm = __int_as_float(((const int*)(wsb + RMIN_OFF))[row]);
    float y2 = ((const float*)(wsb + N2Y_OFF))[row];
    float d = (y2 + rm) * INV_D;
    float rp = INV_D / (d + ALPHA);                // pad: INV_D/inf = 0
    _Float16* p = (_Float16*)(wsb + YP_OFF) + (size_t)row * KP + chunk * 8;
    half8 h = *(half8*)p;
#pragma unroll
    for (int j = 0; j < 8; j++) h[j] = (_Float16)((float)h[j] * rp);
    if (chunk == 18)
        h[4] = (r < NP) ? (_Float16)(rp * y2) : (_Float16)PAD_SENTINEL;
    *(half8*)p = h;
}

// -------- finalize: mean over inputs, mean over images --------------------
__global__ __launch_bounds__(256) void k_final(const char* __restrict__ wsb,
                                               float* __restrict__ out) {
    __shared__ float red[256];
    int tid = threadIdx.x;
    const int* cm = (const int*)(wsb + CMIN_OFF);
    float s = 0.0f;
    for (int i = tid; i < NP; i += 256) {
        s += __int_as_float(cm[i]);
        s += __int_as_float(cm[MP + i]);
    }
    red[tid] = s;
    __syncthreads();
    for (int st = 128; st > 0; st >>= 1) {
        if (tid < st) red[tid] += red[tid + st];
        __syncthreads();
    }
    if (tid == 0) out[0] = red[0] * (0.5f / NP);
}

extern "C" void kernel_launch(void* const* d_in, const int* in_sizes, int n_in,
                              void* d_out, int out_size, void* d_ws, size_t ws_size,
                              hipStream_t stream) {
    const float* x = (const float*)d_in[0];
    const float* y = (const float*)d_in[1];
    char* wsb = (char*)d_ws;
    float* out = (float*)d_out;

    k_build<<<4096, 256, 0, stream>>>(x, y, wsb);
    k_gemm<1><<<dim3(8, 64, IMGS), 256, 0, stream>>>(wsb);
    k_rescale<<<(IMGS * MP * 24) / 256, 256, 0, stream>>>(wsb);
    k_gemm<2><<<dim3(8, 64, IMGS), 256, 0, stream>>>(wsb);
    k_final<<<1, 256, 0, stream>>>(wsb, out);
}

// Round 10
// 157.356 us; speedup vs baseline: 1.6837x; 1.0628x over previous
//
#include <hip/hip_runtime.h>
#include <hip/hip_fp16.h>

// Problem constants
#define IMGS 2
#define OW 90
#define NP 8100                // 90*90 valid patches
#define HW 96
#define CH_STRIDE 9216
#define IMG_STRIDE 27648
#define KP 192                 // padded row stride in halfs (data to 159; rest zero)
#define MP 8192                // padded patch count
#define ALPHA 0.05f
#define INV_D (1.0f/147.0f)
#define PAD_SENTINEL 60000.0f  // finite fp16 value >> any real distance magnitude

typedef _Float16 half8 __attribute__((ext_vector_type(8)));
typedef float floatx4 __attribute__((ext_vector_type(4)));

// async global->LDS, 16B per lane; LDS dest = uniform base + lane*16
#define GLD_LDS16(gp, lp)                                                     \
    __builtin_amdgcn_global_load_lds(                                         \
        (const __attribute__((address_space(1))) void*)(gp),                  \
        (__attribute__((address_space(3))) void*)(lp), 16, 0, 0)

// ws byte offsets
// A matrix = -2*Y, slot147 = 1.0, slot148 = y2 (valid) / 0 (pad)
// B matrix =    X, slot147 = x2 (valid) / 60000 (pad), slot148 = 1 / 0
// => A-row . B-row = x2 + y2 - 2*cross  (the FULL unnormalized distance)
#define XP_OFF   0
#define YP_OFF   (XP_OFF + IMGS*MP*KP*2)
#define RMIN_OFF (YP_OFF + IMGS*MP*KP*2)        // int-bits float [2][8192]
#define CMIN_OFF (RMIN_OFF + IMGS*MP*4)

// -------- fused build + min-init ------------------------------------------
__global__ __launch_bounds__(256) void k_build(const float* __restrict__ x,
                                               const float* __restrict__ y,
                                               char* __restrict__ wsb) {
    int tid = threadIdx.x;
    int hwv = tid >> 5;                      // half-wave 0..7
    int l = tid & 31;
    int grow = blockIdx.x * 8 + hwv;         // 0..32767
    int tensor = grow >> 14;                 // 0 = x(B), 1 = y(A)
    int img = (grow >> 13) & 1;
    int row = grow & (MP - 1);
    const float* src = (tensor ? y : x) + img * IMG_STRIDE;
    int py = row / OW, px = row - py * OW;
    bool rvalid = row < NP;

    float vals[8];
#pragma unroll
    for (int j = 0; j < 8; j++) {
        int k = l * 8 + j;
        float v = 0.0f;
        if (rvalid && k < 147) {
            int c = k / 49;
            int rm = k - c * 49;
            int dy = rm / 7, dx = rm - dy * 7;
            v = src[c * CH_STRIDE + (py + dy) * HW + px + dx];
        }
        vals[j] = (float)(_Float16)v;        // round through fp16 (ref casts first)
    }
    float ss16 = 0.0f;                       // squared norm of fp16-rounded row
#pragma unroll
    for (int j = 0; j < 8; j++) ss16 = fmaf(vals[j], vals[j], ss16);
#pragma unroll
    for (int m = 1; m < 32; m <<= 1) ss16 += __shfl_xor(ss16, m, 32);

    half8 h;
#pragma unroll
    for (int j = 0; j < 8; j++) {
        float f = vals[j];
        if (tensor) f *= -2.0f;              // A = -2*Y (exact in fp16)
        h[j] = (_Float16)f;
    }
    if (l == 18) {                           // k=147 is j=3, k=148 is j=4
        if (tensor) {                        // A (Y): slot147=1, slot148=y2
            h[3] = (_Float16)1.0f;
            h[4] = rvalid ? (_Float16)ss16 : (_Float16)0.0f;
        } else {                             // B (X): slot147=x2/sentinel, 148=1/0
            h[3] = rvalid ? (_Float16)ss16 : (_Float16)PAD_SENTINEL;
            h[4] = rvalid ? (_Float16)1.0f : (_Float16)0.0f;
        }
    }
    if (l < 24) {
        _Float16* dst = (_Float16*)(wsb + (tensor ? YP_OFF : XP_OFF)) +
                        ((size_t)img * MP + row) * KP + l * 8;
        *(half8*)dst = h;
    }
    if (tid < 8) {                           // min-array init (ws is re-poisoned)
        int gi = blockIdx.x * 8 + tid;
        if (gi < IMGS * MP)
            ((int*)(wsb + RMIN_OFF))[gi] = 0x7f800000;
        else
            ((int*)(wsb + CMIN_OFF))[gi - IMGS * MP] = 0x7f800000;
    }
}

// -------- resident-operand streaming GEMM, rf = ALL 128 resident rows -----
// LDS-BW analysis (r9 PMC): MfmaUtil was 388/1090 cyc = LDS-traffic-bound.
// Fix: each wave holds all 128 resident rows (rf[8][5], 160 VGPR) and
// streams only 16 rows/step (1 sf read per ks) -> LDS reads halved.
// Min-dim on the C-COLUMN (resident) side for both passes:
//   acc[i] = mfma(sf, rf[i], acc[i]); fold rows+steps in 8 min-regs.
// PASS 1: resident = Y, stream X:  acc = x2+y2-2c; col t min -> RMIN.
// PASS 2: resident = X, stream A scaled on the fly by r' = INV_D/(rm*INV_D+a):
//   acc = r'(x2+y2-2c); col i min -> CMIN. Pad stream rows: r'=0 + sentinel.
#define R2OFF 8192   // halfs: region2 base within a 10240-half buffer

#define STAGE64(mat, buf)                                                      \
    {                                                                          \
        int rb_ = w * 16;                                                      \
        _Pragma("unroll") for (int g_ = 0; g_ < 4; g_++) {                     \
            int r_ = rb_ + g_ * 4 + (lane >> 4);                               \
            int gc_ = (lane & 15) ^ (r_ & 7);                                  \
            GLD_LDS16((mat) + (size_t)r_ * KP + gc_ * 8,                       \
                      (buf) + (rb_ + g_ * 4) * 128);                           \
        }                                                                      \
        int r2_ = rb_ + (lane >> 2);                                           \
        int gc2_ = (lane & 3) ^ ((r2_ >> 1) & 3);                              \
        GLD_LDS16((mat) + (size_t)r2_ * KP + 128 + gc2_ * 8,                   \
                  (buf) + R2OFF + rb_ * 32);                                   \
    }

#define READFRAG(buf, row, ks)                                                 \
    ((ks) < 4 ? *(const half8*)(&(buf)[(row) * 128 +                           \
                                       ((((ks) * 4 + quad) ^ ((row) & 7)) * 8)]) \
              : *(const half8*)(&(buf)[R2OFF + (row) * 32 +                    \
                                       ((quad ^ (((row) >> 1) & 3)) * 8)]))

template <int PASS>
__global__ __launch_bounds__(256, 2) void k_gemm(char* __restrict__ wsb) {
    __shared__ __align__(16) _Float16 Buf[2][10240];   // 2 x 20 KB
    int tid = threadIdx.x;
    int lane = tid & 63, w = tid >> 6;
    int quad = lane >> 4, col16 = lane & 15;
    int q = blockIdx.x;                      // octant: 16 streamed 64-row tiles
    int rtile = blockIdx.y;                  // resident 128-row tile
    int img = blockIdx.z;

    const _Float16* Res = (const _Float16*)(wsb + (PASS == 1 ? YP_OFF : XP_OFF)) +
                          ((size_t)img * MP + rtile * 128) * KP;
    const _Float16* Str = (const _Float16*)(wsb + (PASS == 1 ? XP_OFF : YP_OFF)) +
                          (size_t)img * MP * KP;

    // ---- prologue: resident 128 rows -> both buffers -> 40 register frags
    STAGE64(Res, Buf[0]);
    STAGE64(Res + (size_t)64 * KP, Buf[1]);
    __syncthreads();
    half8 rf[8][5];
#pragma unroll
    for (int i = 0; i < 8; i++) {
        const _Float16* rb = (i < 4) ? Buf[0] : Buf[1];
#pragma unroll
        for (int c = 0; c < 5; c++)
            rf[i][c] = READFRAG(rb, (i & 3) * 16 + col16, c);
    }
    __syncthreads();                         // rf reads drained before overwrite
    STAGE64(Str + (size_t)(q * 16) * 64 * KP, Buf[0]);   // tile 0 -> buf0

    float mn[8];
#pragma unroll
    for (int i = 0; i < 8; i++) mn[i] = 1e30f;
    const int* RM = (const int*)(wsb + RMIN_OFF) + img * MP;
    int srow = w * 16 + col16;               // this lane's streamed row (A m-dim)

    for (int s = 0; s < 16; s++) {
        __syncthreads();                     // drains prefetch of s; reads of s-1 done
        if (s < 15)
            STAGE64(Str + (size_t)(q * 16 + s + 1) * 64 * KP, Buf[(s + 1) & 1]);
        const _Float16* sb = Buf[s & 1];

        _Float16 rp = (_Float16)1.0f;
        bool pad = false;
        if (PASS == 2) {                     // r' for this lane's streamed row
            int rmb = RM[(q * 16 + s) * 64 + srow];
            pad = (rmb == 0x7f800000);       // +inf -> pad row
            float d = __int_as_float(rmb) * INV_D;
            rp = (_Float16)(INV_D / (d + ALPHA));   // pad: INV_D/inf = 0
        }

        floatx4 acc[8];
#pragma unroll
        for (int i = 0; i < 8; i++) acc[i] = (floatx4){0.f, 0.f, 0.f, 0.f};
#pragma unroll
        for (int ks = 0; ks < 5; ks++) {
            half8 sf = READFRAG(sb, srow, ks);
            if (PASS == 2) {
                half8 rpv = {rp, rp, rp, rp, rp, rp, rp, rp};
                sf = sf * rpv;               // scale whole row by r' (pk_mul_f16)
                if (ks == 4 && pad && quad == 2)
                    sf[4] = (_Float16)PAD_SENTINEL;   // k=148 sentinel for pad rows
            }
#pragma unroll
            for (int i = 0; i < 8; i++)
                acc[i] = __builtin_amdgcn_mfma_f32_16x16x32_f16(
                    sf, rf[i][ks], acc[i], 0, 0, 0);
        }
#pragma unroll
        for (int i = 0; i < 8; i++)
            mn[i] = fminf(mn[i], fminf(fminf(acc[i][0], acc[i][1]),
                                       fminf(acc[i][2], acc[i][3])));
    }

    // ---- final: min across quads (streamed rows) + one atomicMin per col
    int* dst = (int*)(wsb + (PASS == 1 ? RMIN_OFF : CMIN_OFF)) + img * MP;
#pragma unroll
    for (int i = 0; i < 8; i++) {
        float best = mn[i];
        best = fminf(best, __shfl_xor(best, 16, 64));
        best = fminf(best, __shfl_xor(best, 32, 64));
        int cg = rtile * 128 + i * 16 + col16;
        if (quad == 0 && cg < NP)
            atomicMin(dst + cg, __float_as_int(best));
    }
}

// -------- finalize: mean over inputs, mean over images --------------------
__global__ __launch_bounds__(256) void k_final(const char* __restrict__ wsb,
                                               float* __restrict__ out) {
    __shared__ float red[256];
    int tid = threadIdx.x;
    const int* cm = (const int*)(wsb + CMIN_OFF);
    float s = 0.0f;
    for (int i = tid; i < NP; i += 256) {
        s += __int_as_float(cm[i]);
        s += __int_as_float(cm[MP + i]);
    }
    red[tid] = s;
    __syncthreads();
    for (int st = 128; st > 0; st >>= 1) {
        if (tid < st) red[tid] += red[tid + st];
        __syncthreads();
    }
    if (tid == 0) out[0] = red[0] * (0.5f / NP);
}

extern "C" void kernel_launch(void* const* d_in, const int* in_sizes, int n_in,
                              void* d_out, int out_size, void* d_ws, size_t ws_size,
                              hipStream_t stream) {
    const float* x = (const float*)d_in[0];
    const float* y = (const float*)d_in[1];
    char* wsb = (char*)d_ws;
    float* out = (float*)d_out;

    k_build<<<4096, 256, 0, stream>>>(x, y, wsb);
    k_gemm<1><<<dim3(8, 64, IMGS), 256, 0, stream>>>(wsb);
    k_gemm<2><<<dim3(8, 64, IMGS), 256, 0, stream>>>(wsb);
    k_final<<<1, 256, 0, stream>>>(wsb, out);
}